// Round 9
// baseline (26.433 us; speedup 1.0000x reference)
//
#include <hip/hip_runtime.h>
#include <math.h>

#define BLOCK 256
#define WPB   (BLOCK / 64)     // 4 waves per block
#define K     2048
#define ROWS_PER_WAVE 2        // one clustered pair per wave (nt-era re-sweep)
#define GRID  2048             // 16384 rows / (4 waves * 2 rows)

typedef float f32x4 __attribute__((ext_vector_type(4)));

__device__ __forceinline__ float sq4(f32x4 v) {
    return v.x * v.x + v.y * v.y + v.z * v.z + v.w * v.w;
}

// Non-temporal dwordx4 load: nt bit skips cache allocation (streaming read,
// zero intra-call reuse). R8 proved this is worth ~9% on this kernel.
__device__ __forceinline__ f32x4 ldnt(const f32x4* p) {
    return __builtin_nontemporal_load(p);
}

// Phase 1: 2048 blk x 256 thr, 2 adjacent rows/wave, 16 nt loads in flight.
// Lower VGPR than R8 (one pair live, not two sequential pairs) -> more
// resident waves -> more outstanding loads device-wide.
__global__ __launch_bounds__(BLOCK) void row_ssq_kernel(
    const float* __restrict__ d, float* __restrict__ partials) {
    const int wave = threadIdx.x >> 6;
    const int lane = threadIdx.x & 63;
    const int base = (blockIdx.x * WPB + wave) * ROWS_PER_WAVE;

    const f32x4* __restrict__ pa =
        reinterpret_cast<const f32x4*>(d + (size_t)base * K);
    const f32x4* __restrict__ pb =
        reinterpret_cast<const f32x4*>(d + (size_t)(base + 1) * K);
    f32x4 a0 = ldnt(pa + lane + 64 * 0), b0 = ldnt(pb + lane + 64 * 0);
    f32x4 a1 = ldnt(pa + lane + 64 * 1), b1 = ldnt(pb + lane + 64 * 1);
    f32x4 a2 = ldnt(pa + lane + 64 * 2), b2 = ldnt(pb + lane + 64 * 2);
    f32x4 a3 = ldnt(pa + lane + 64 * 3), b3 = ldnt(pb + lane + 64 * 3);
    f32x4 a4 = ldnt(pa + lane + 64 * 4), b4 = ldnt(pb + lane + 64 * 4);
    f32x4 a5 = ldnt(pa + lane + 64 * 5), b5 = ldnt(pb + lane + 64 * 5);
    f32x4 a6 = ldnt(pa + lane + 64 * 6), b6 = ldnt(pb + lane + 64 * 6);
    f32x4 a7 = ldnt(pa + lane + 64 * 7), b7 = ldnt(pb + lane + 64 * 7);

    float sa = ((sq4(a0) + sq4(a1)) + (sq4(a2) + sq4(a3))) +
               ((sq4(a4) + sq4(a5)) + (sq4(a6) + sq4(a7)));
    float sb = ((sq4(b0) + sq4(b1)) + (sq4(b2) + sq4(b3))) +
               ((sq4(b4) + sq4(b5)) + (sq4(b6) + sq4(b7)));
#pragma unroll
    for (int off = 32; off >= 1; off >>= 1) {
        sa += __shfl_xor(sa, off);
        sb += __shfl_xor(sb, off);
    }
    float ta = sa - 1.0f, tb = sb - 1.0f;
    float acc = ta * ta + tb * tb;

    __shared__ float smem[WPB];
    if (lane == 0) smem[wave] = acc;
    __syncthreads();
    if (threadIdx.x == 0)
        partials[blockIdx.x] = smem[0] + smem[1] + smem[2] + smem[3];
}

// Phase 2: one wave, 2048 partials = 8 float4 per lane.
__global__ __launch_bounds__(64) void finalize_kernel(
    const float* __restrict__ partials, float* __restrict__ out) {
    const int lane = threadIdx.x;
    const f32x4* __restrict__ p = reinterpret_cast<const f32x4*>(partials);
    float acc = 0.0f;
#pragma unroll
    for (int i = 0; i < GRID / 4 / 64; ++i) {
        f32x4 v = p[lane + 64 * i];
        acc += (v.x + v.y) + (v.z + v.w);
    }
#pragma unroll
    for (int off = 32; off >= 1; off >>= 1)
        acc += __shfl_xor(acc, off);
    if (lane == 0) out[0] = 0.001f * sqrtf(acc);
}

extern "C" void kernel_launch(void* const* d_in, const int* in_sizes, int n_in,
                              void* d_out, int out_size, void* d_ws, size_t ws_size,
                              hipStream_t stream) {
    const float* d = (const float*)d_in[0];
    float* out = (float*)d_out;
    float* partials = (float*)d_ws;   // GRID floats

    row_ssq_kernel<<<GRID, BLOCK, 0, stream>>>(d, partials);
    finalize_kernel<<<1, 64, 0, stream>>>(partials, out);
}